// Round 1
// baseline (126.635 us; speedup 1.0000x reference)
//
#include <hip/hip_runtime.h>
#include <hip/hip_bf16.h>

// Problem constants (fixed by the reference: B=8, N=512, E=128, H=64)
#define BB 8
#define NN 512
#define EE 128
#define HH 64
#define EP (NN * (NN - 1))        // 261632 edges per batch
#define ECNT (BB * EP)            // 2093056 total edges
// d_out layout (floats): [edge_index row0 | edge_index row1 | edge_weights | alpha]
#define OFF_EI0 0
#define OFF_EI1 ECNT
#define OFF_EW  (2 * ECNT)        // 4186112
#define OFF_AL  (3 * ECNT)        // 6279168; alpha = 8*512*512 = 2097152
// total out_size = 8376320

// ---------------- Kernel A: pj = h@W1 + b, pk = h@W2 ----------------
// one block (64 threads) per row i of h (4096 rows)
__global__ void k_proj(const float* __restrict__ h, const float* __restrict__ W,
                       const float* __restrict__ bvec,
                       float* __restrict__ pj, float* __restrict__ pk) {
    __shared__ float hrow[EE];
    const int i = blockIdx.x;
    const int c = threadIdx.x;            // 0..63 output column
    hrow[c]      = h[i * EE + c];
    hrow[c + 64] = h[i * EE + 64 + c];
    __syncthreads();
    float accj = 0.f, acck = 0.f;
#pragma unroll 8
    for (int e = 0; e < EE; ++e) {
        const float hv = hrow[e];                       // LDS broadcast
        accj = fmaf(hv, W[e * HH + c], accj);           // W1 row e
        acck = fmaf(hv, W[(EE + e) * HH + c], acck);    // W2 row e
    }
    pj[i * HH + c] = accj + bvec[c];   // fold bias into pj
    pk[i * HH + c] = acck;
}

// ---------------- Kernel B: e scores + row softmax -> alpha ----------------
// one block (256 threads) per (b, j) row; thread owns k = tid and tid+256
__global__ void k_attn(const float* __restrict__ pj, const float* __restrict__ pk,
                       const float* __restrict__ att, float* __restrict__ alpha) {
    const int bj = blockIdx.x;           // b*512 + j
    const int b  = bj >> 9;
    const int tid = threadIdx.x;
    const int lane = tid & 63;
    const int wid  = tid >> 6;

    __shared__ float4 pj4[HH / 4];
    __shared__ float4 ap4[HH / 4];
    __shared__ float4 an4[HH / 4];
    __shared__ float red[4];

    if (tid < HH / 4) {
        pj4[tid] = reinterpret_cast<const float4*>(pj + (size_t)bj * HH)[tid];
        float4 a = reinterpret_cast<const float4*>(att)[tid];
        ap4[tid] = a;
        float4 an; an.x = 0.2f * a.x; an.y = 0.2f * a.y; an.z = 0.2f * a.z; an.w = 0.2f * a.w;
        an4[tid] = an;
    }
    __syncthreads();

    const int k0 = tid;
    const int k1 = tid + 256;
    const float4* pkA = reinterpret_cast<const float4*>(pk + ((size_t)b * NN + k0) * HH);
    const float4* pkB = reinterpret_cast<const float4*>(pk + ((size_t)b * NN + k1) * HH);

    float acc0 = 0.f, acc1 = 0.f;
#pragma unroll
    for (int q = 0; q < HH / 4; ++q) {
        const float4 pw = pj4[q];
        const float4 ap = ap4[q];
        const float4 an = an4[q];
        const float4 v0 = pkA[q];
        const float4 v1 = pkB[q];
        float s;
        s = pw.x + v0.x; acc0 = fmaf(s, (s > 0.f) ? ap.x : an.x, acc0);
        s = pw.y + v0.y; acc0 = fmaf(s, (s > 0.f) ? ap.y : an.y, acc0);
        s = pw.z + v0.z; acc0 = fmaf(s, (s > 0.f) ? ap.z : an.z, acc0);
        s = pw.w + v0.w; acc0 = fmaf(s, (s > 0.f) ? ap.w : an.w, acc0);
        s = pw.x + v1.x; acc1 = fmaf(s, (s > 0.f) ? ap.x : an.x, acc1);
        s = pw.y + v1.y; acc1 = fmaf(s, (s > 0.f) ? ap.y : an.y, acc1);
        s = pw.z + v1.z; acc1 = fmaf(s, (s > 0.f) ? ap.z : an.z, acc1);
        s = pw.w + v1.w; acc1 = fmaf(s, (s > 0.f) ? ap.w : an.w, acc1);
    }

    // block max over 512 values
    float m = fmaxf(acc0, acc1);
#pragma unroll
    for (int off = 32; off >= 1; off >>= 1)
        m = fmaxf(m, __shfl_xor(m, off, 64));
    if (lane == 0) red[wid] = m;
    __syncthreads();
    m = fmaxf(fmaxf(red[0], red[1]), fmaxf(red[2], red[3]));
    __syncthreads();

    const float p0 = __expf(acc0 - m);
    const float p1 = __expf(acc1 - m);
    float s = p0 + p1;
#pragma unroll
    for (int off = 32; off >= 1; off >>= 1)
        s += __shfl_xor(s, off, 64);
    if (lane == 0) red[wid] = s;
    __syncthreads();
    s = (red[0] + red[1]) + (red[2] + red[3]);
    const float inv = 1.0f / s;

    float* arow = alpha + (size_t)bj * NN;
    arow[k0] = p0 * inv;
    arow[k1] = p1 * inv;
}

// ---------------- Kernel C: edge_index + edge_weights ----------------
// one thread per edge; alpha already in d_out
__global__ void k_edges(const float* __restrict__ alpha, float* __restrict__ out) {
    const unsigned idx = blockIdx.x * 256u + threadIdx.x;   // < ECNT (grid exact)
    const unsigned b = idx / EP;
    const unsigned e = idx - b * EP;
    const unsigned j = e / (NN - 1);
    const unsigned t = e - j * (NN - 1);
    const unsigned k = t + (t >= j ? 1u : 0u);

    const float* A = alpha + (size_t)b * NN * NN;
    const float w = 0.5f * (A[j * NN + k] + A[k * NN + j]);

    const float base = (float)(b * NN);
    out[OFF_EI0 + idx] = base + (float)j;
    out[OFF_EI1 + idx] = base + (float)k;
    out[OFF_EW  + idx] = w;
}

extern "C" void kernel_launch(void* const* d_in, const int* in_sizes, int n_in,
                              void* d_out, int out_size, void* d_ws, size_t ws_size,
                              hipStream_t stream) {
    const float* h    = (const float*)d_in[0];
    const float* W    = (const float*)d_in[1];
    const float* bvec = (const float*)d_in[2];
    const float* att  = (const float*)d_in[3];
    float* out = (float*)d_out;

    float* pj = (float*)d_ws;                       // 4096*64 floats = 1 MB
    float* pk = pj + (size_t)BB * NN * HH;          // 1 MB

    float* alpha = out + OFF_AL;

    k_proj<<<BB * NN, 64, 0, stream>>>(h, W, bvec, pj, pk);
    k_attn<<<BB * NN, 256, 0, stream>>>(pj, pk, att, alpha);
    k_edges<<<ECNT / 256, 256, 0, stream>>>(alpha, out);
}

// Round 2
// 47.255 us; speedup vs baseline: 2.6798x; 2.6798x over previous
//
#include <hip/hip_runtime.h>
#include <hip/hip_bf16.h>

// Problem constants (fixed by the reference: B=8, N=512, E=128, H=64)
#define BB 8
#define NN 512
#define EE 128
#define HH 64
#define EP (NN * (NN - 1))        // 261632 edges per batch
#define ECNT (BB * EP)            // 2093056 total edges
// d_out layout (floats): [edge_index row0 | edge_index row1 | edge_weights | alpha]
#define OFF_EI0 0
#define OFF_EI1 ECNT
#define OFF_EW  (2 * ECNT)
#define OFF_AL  (3 * ECNT)

// ---------------- Kernel A: pj = h@W1 + b (row-major), pkT = (h@W2)^T ----------------
// one block (64 threads) per row i of h (4096 rows)
__global__ void k_proj(const float* __restrict__ h, const float* __restrict__ W,
                       const float* __restrict__ bvec,
                       float* __restrict__ pj, float* __restrict__ pkT) {
    __shared__ float hrow[EE];
    const int i = blockIdx.x;
    const int c = threadIdx.x;            // 0..63 output column (h)
    hrow[c]      = h[i * EE + c];
    hrow[c + 64] = h[i * EE + 64 + c];
    __syncthreads();
    float accj = 0.f, acck = 0.f;
#pragma unroll 8
    for (int e = 0; e < EE; ++e) {
        const float hv = hrow[e];                       // LDS broadcast
        accj = fmaf(hv, W[e * HH + c], accj);           // W1 row e
        acck = fmaf(hv, W[(EE + e) * HH + c], acck);    // W2 row e
    }
    pj[i * HH + c] = accj + bvec[c];      // bias folded into pj
    const int b = i >> 9;
    const int n = i & 511;
    pkT[((size_t)b * HH + c) * NN + n] = acck;   // h-major transpose (scattered, 1MB once)
}

// ---------------- Kernel B: scores + softmax, pk in registers ----------------
// block = 512 threads = full k row; thread tid <-> k; 8 j rows per block
__global__ __launch_bounds__(512, 4) void k_attn(
        const float* __restrict__ pj, const float* __restrict__ pkT,
        const float* __restrict__ att, float* __restrict__ alpha) {
    const int bid   = blockIdx.x;
    const int b     = bid >> 6;           // 8 batches
    const int jbase = (bid & 63) * 8;     // 64 slices of 8 j's
    const int tid   = threadIdx.x;        // = k
    const int lane  = tid & 63;
    const int wid   = tid >> 6;

    __shared__ float  pj_s[8][HH];        // 2 KB
    __shared__ float4 ap4[HH / 4];
    __shared__ float4 an4[HH / 4];
    __shared__ float  e_s[8][NN];         // 16 KB

    // stage pj rows (8 x 64) — one float per thread, coalesced
    pj_s[wid][lane] = pj[((size_t)b * NN + jbase + wid) * HH + lane];
    if (tid < HH / 4) {
        float4 a = reinterpret_cast<const float4*>(att)[tid];
        ap4[tid] = a;
        float4 an; an.x = 0.2f * a.x; an.y = 0.2f * a.y; an.z = 0.2f * a.z; an.w = 0.2f * a.w;
        an4[tid] = an;
    }

    // this thread's pk row (k = tid): 64 coalesced loads from pkT
    float pkr[HH];
    const float* pkb = pkT + (size_t)b * HH * NN + tid;
#pragma unroll
    for (int hh = 0; hh < HH; ++hh) pkr[hh] = pkb[hh * NN];

    __syncthreads();

    float acc0[8], acc1[8];
#pragma unroll
    for (int j = 0; j < 8; ++j) { acc0[j] = 0.f; acc1[j] = 0.f; }

#pragma unroll
    for (int q = 0; q < HH / 4; ++q) {
        const float4 ap = ap4[q];
        const float4 an = an4[q];
        const float k0 = pkr[4 * q + 0];
        const float k1 = pkr[4 * q + 1];
        const float k2 = pkr[4 * q + 2];
        const float k3 = pkr[4 * q + 3];
#pragma unroll
        for (int j = 0; j < 8; ++j) {
            const float4 pw = reinterpret_cast<const float4*>(&pj_s[j][0])[q]; // broadcast
            float s;
            s = pw.x + k0; acc0[j] = fmaf(s, (s > 0.f) ? ap.x : an.x, acc0[j]);
            s = pw.y + k1; acc1[j] = fmaf(s, (s > 0.f) ? ap.y : an.y, acc1[j]);
            s = pw.z + k2; acc0[j] = fmaf(s, (s > 0.f) ? ap.z : an.z, acc0[j]);
            s = pw.w + k3; acc1[j] = fmaf(s, (s > 0.f) ? ap.w : an.w, acc1[j]);
        }
    }

    // park score rows in LDS (lane-consecutive, conflict-free)
#pragma unroll
    for (int j = 0; j < 8; ++j) e_s[j][tid] = acc0[j] + acc1[j];
    __syncthreads();

    // softmax: wave wid owns row jbase+wid (512 values, 8 per lane)
    {
        float v[8];
        float m = -1e30f;
#pragma unroll
        for (int i2 = 0; i2 < 8; ++i2) {
            v[i2] = e_s[wid][lane + 64 * i2];
            m = fmaxf(m, v[i2]);
        }
#pragma unroll
        for (int off = 32; off >= 1; off >>= 1) m = fmaxf(m, __shfl_xor(m, off, 64));
        float s = 0.f;
#pragma unroll
        for (int i2 = 0; i2 < 8; ++i2) { v[i2] = __expf(v[i2] - m); s += v[i2]; }
#pragma unroll
        for (int off = 32; off >= 1; off >>= 1) s += __shfl_xor(s, off, 64);
        const float inv = 1.0f / s;
        float* arow = alpha + ((size_t)b * NN + jbase + wid) * NN;
#pragma unroll
        for (int i2 = 0; i2 < 8; ++i2) arow[lane + 64 * i2] = v[i2] * inv;
    }
}

// ---------------- Kernel C: edge_index + edge_weights, LDS tile transpose ----------------
// block = 256 threads handles a 64x64 (j,k) tile; grid = 8 b * 8 jt * 8 kt
__global__ void k_edges(const float* __restrict__ alpha, float* __restrict__ out) {
    const int bid   = blockIdx.x;
    const int b     = bid >> 6;
    const int jt    = (bid >> 3) & 7;
    const int kt    = bid & 7;
    const int jbase = jt * 64;
    const int kbase = kt * 64;
    const int tid   = threadIdx.x;
    const int c     = tid & 63;           // within-tile column
    const int r0    = tid >> 6;           // 0..3

    __shared__ float at[64][65];          // at[jj][kk] = A[kbase+kk][jbase+jj]

    const float* A = alpha + (size_t)b * NN * NN;

#pragma unroll
    for (int i = 0; i < 16; ++i) {
        const int r = i * 4 + r0;                       // k-row within tile
        at[c][r] = A[(kbase + r) * NN + jbase + c];     // coalesced read, padded store
    }
    __syncthreads();

    const float fb = (float)(b * NN);
#pragma unroll
    for (int i = 0; i < 16; ++i) {
        const int jj = i * 4 + r0;
        const int j  = jbase + jj;
        const int k  = kbase + c;
        if (k == j) continue;
        const float w = 0.5f * (A[j * NN + k] + at[jj][c]);
        const unsigned t   = (unsigned)k - ((k > j) ? 1u : 0u);
        const unsigned idx = (unsigned)b * EP + (unsigned)j * (NN - 1) + t;
        out[OFF_EI0 + idx] = fb + (float)j;
        out[OFF_EI1 + idx] = fb + (float)k;
        out[OFF_EW  + idx] = w;
    }
}

extern "C" void kernel_launch(void* const* d_in, const int* in_sizes, int n_in,
                              void* d_out, int out_size, void* d_ws, size_t ws_size,
                              hipStream_t stream) {
    const float* h    = (const float*)d_in[0];
    const float* W    = (const float*)d_in[1];
    const float* bvec = (const float*)d_in[2];
    const float* att  = (const float*)d_in[3];
    float* out = (float*)d_out;

    float* pj  = (float*)d_ws;                       // 4096*64 floats = 1 MB
    float* pkT = pj + (size_t)BB * NN * HH;          // 1 MB, h-major

    float* alpha = out + OFF_AL;

    k_proj <<<BB * NN, 64, 0, stream>>>(h, W, bvec, pj, pkT);
    k_attn <<<BB * 64, 512, 0, stream>>>(pj, pkT, att, alpha);
    k_edges<<<BB * 64, 256, 0, stream>>>(alpha, out);
}

// Round 3
// 39.974 us; speedup vs baseline: 3.1680x; 1.1822x over previous
//
#include <hip/hip_runtime.h>
#include <hip/hip_bf16.h>

// Problem constants (fixed by the reference: B=8, N=512, E=128, H=64)
#define BB 8
#define NN 512
#define EE 128
#define HH 64
#define EP (NN * (NN - 1))        // 261632 edges per batch
#define ECNT (BB * EP)            // 2093056 total edges
// d_out layout (floats): [edge_index row0 | edge_index row1 | edge_weights | alpha]
#define OFF_EI0 0
#define OFF_EI1 ECNT
#define OFF_EW  (2 * ECNT)
#define OFF_AL  (3 * ECNT)

// ---------------- Kernel A: projections + rank-1 terms ----------------
// pjb = h@W1 + b (row-major), pkT = (h@W2)^T (h-major),
// cj[i] = 0.6*sum_h att_h*pjb[i][h], dk[i] = 0.6*sum_h att_h*pk[i][h]
// block = 256 threads = 4 waves; handles 8 rows of h; wave w owns rows {w, w+4}
__global__ __launch_bounds__(256) void k_proj(
        const float* __restrict__ h, const float* __restrict__ W,
        const float* __restrict__ bvec, const float* __restrict__ att,
        float* __restrict__ pj, float* __restrict__ pkT,
        float* __restrict__ cj, float* __restrict__ dk) {
    const int row0 = blockIdx.x * 8;
    const int tid  = threadIdx.x;
    const int c    = tid & 63;                       // output column (h)
    const int w    = __builtin_amdgcn_readfirstlane(tid >> 6);   // wave id, formally uniform

    // rows this wave computes: rA = w, rB = w+4 (global rows row0+r)
    const float* hA = h + (size_t)(row0 + w) * EE;       // uniform base -> s_loads
    const float* hB = h + (size_t)(row0 + w + 4) * EE;

    float aj0 = 0.f, ak0 = 0.f, aj1 = 0.f, ak1 = 0.f;
#pragma unroll
    for (int e = 0; e < EE; ++e) {
        const float w1 = W[e * HH + c];              // coalesced vector load
        const float w2 = W[(EE + e) * HH + c];
        const float h0 = hA[e];                      // scalar (SGPR) broadcast
        const float h1 = hB[e];
        aj0 = fmaf(h0, w1, aj0);
        ak0 = fmaf(h0, w2, ak0);
        aj1 = fmaf(h1, w1, aj1);
        ak1 = fmaf(h1, w2, ak1);
    }
    const float bb = bvec[c];
    aj0 += bb; aj1 += bb;

    const float a6 = 0.6f * att[c];

    const int iA = row0 + w;
    const int iB = row0 + w + 4;
    // row-major pj (+bias folded)
    pj[iA * HH + c] = aj0;
    pj[iB * HH + c] = aj1;
    // h-major pk transpose
    {
        const int bA = iA >> 9, nA = iA & 511;
        const int bB = iB >> 9, nB = iB & 511;
        pkT[((size_t)bA * HH + c) * NN + nA] = ak0;
        pkT[((size_t)bB * HH + c) * NN + nB] = ak1;
    }
    // rank-1 reductions (wave-wide)
    float c0 = a6 * aj0, d0 = a6 * ak0, c1 = a6 * aj1, d1 = a6 * ak1;
#pragma unroll
    for (int off = 32; off >= 1; off >>= 1) {
        c0 += __shfl_xor(c0, off, 64);
        d0 += __shfl_xor(d0, off, 64);
        c1 += __shfl_xor(c1, off, 64);
        d1 += __shfl_xor(d1, off, 64);
    }
    if (c == 0) {
        cj[iA] = c0; dk[iA] = d0;
        cj[iB] = c1; dk[iB] = d1;
    }
}

// ---------------- Kernel B: e = cj + dk + 0.4*sum att|s|, softmax ----------------
// block = 512 threads = full k row; thread tid <-> k; 8 j rows per block
__global__ __launch_bounds__(512, 4) void k_attn(
        const float* __restrict__ pj, const float* __restrict__ pkT,
        const float* __restrict__ att, const float* __restrict__ cj,
        const float* __restrict__ dk, float* __restrict__ alpha) {
    const int bid   = blockIdx.x;
    const int b     = bid >> 6;
    const int jbase = (bid & 63) * 8;
    const int tid   = threadIdx.x;        // = k
    const int lane  = tid & 63;
    const int wid   = tid >> 6;

    __shared__ float e_s[8][NN];          // 16 KB

    // this thread's pk row (k = tid): 64 coalesced loads from pkT
    float pkr[HH];
    const float* pkb = pkT + (size_t)b * HH * NN + tid;
#pragma unroll
    for (int hh = 0; hh < HH; ++hh) pkr[hh] = pkb[hh * NN];
    const float dkv = dk[b * NN + tid];

    // block-uniform bases -> compiler scalarizes these loads to s_load
    const float* pjb = pj + ((size_t)b * NN + jbase) * HH;
    const float* cjb = cj + b * NN + jbase;

    float acc[8];
#pragma unroll
    for (int j = 0; j < 8; ++j) acc[j] = 0.f;

#pragma unroll
    for (int q = 0; q < HH / 4; ++q) {
        const float a0 = att[4 * q + 0];          // uniform -> SGPR
        const float a1 = att[4 * q + 1];
        const float a2 = att[4 * q + 2];
        const float a3 = att[4 * q + 3];
        const float k0 = pkr[4 * q + 0];
        const float k1 = pkr[4 * q + 1];
        const float k2 = pkr[4 * q + 2];
        const float k3 = pkr[4 * q + 3];
#pragma unroll
        for (int j = 0; j < 8; ++j) {
            const float p0 = pjb[j * HH + 4 * q + 0];   // uniform -> SGPR
            const float p1 = pjb[j * HH + 4 * q + 1];
            const float p2 = pjb[j * HH + 4 * q + 2];
            const float p3 = pjb[j * HH + 4 * q + 3];
            float s;
            s = p0 + k0; acc[j] = fmaf(a0, fabsf(s), acc[j]);
            s = p1 + k1; acc[j] = fmaf(a1, fabsf(s), acc[j]);
            s = p2 + k2; acc[j] = fmaf(a2, fabsf(s), acc[j]);
            s = p3 + k3; acc[j] = fmaf(a3, fabsf(s), acc[j]);
        }
    }

    // e rows into LDS (lane-consecutive, conflict-free)
#pragma unroll
    for (int j = 0; j < 8; ++j)
        e_s[j][tid] = fmaf(0.4f, acc[j], cjb[j] + dkv);
    __syncthreads();

    // softmax: wave wid owns row jbase+wid (512 values, 8 per lane)
    {
        float v[8];
        float m = -1e30f;
#pragma unroll
        for (int i2 = 0; i2 < 8; ++i2) {
            v[i2] = e_s[wid][lane + 64 * i2];
            m = fmaxf(m, v[i2]);
        }
#pragma unroll
        for (int off = 32; off >= 1; off >>= 1) m = fmaxf(m, __shfl_xor(m, off, 64));
        float s = 0.f;
#pragma unroll
        for (int i2 = 0; i2 < 8; ++i2) { v[i2] = __expf(v[i2] - m); s += v[i2]; }
#pragma unroll
        for (int off = 32; off >= 1; off >>= 1) s += __shfl_xor(s, off, 64);
        const float inv = 1.0f / s;
        float* arow = alpha + ((size_t)b * NN + jbase + wid) * NN;
#pragma unroll
        for (int i2 = 0; i2 < 8; ++i2) arow[lane + 64 * i2] = v[i2] * inv;
    }
}

// ---------------- Kernel C: edge_index + edge_weights, LDS tile transpose ----------------
// block = 256 threads handles a 64x64 (j,k) tile; grid = 8 b * 8 jt * 8 kt
__global__ void k_edges(const float* __restrict__ alpha, float* __restrict__ out) {
    const int bid   = blockIdx.x;
    const int b     = bid >> 6;
    const int jt    = (bid >> 3) & 7;
    const int kt    = bid & 7;
    const int jbase = jt * 64;
    const int kbase = kt * 64;
    const int tid   = threadIdx.x;
    const int c     = tid & 63;           // within-tile column
    const int r0    = tid >> 6;           // 0..3

    __shared__ float at[64][65];          // at[jj][kk] = A[kbase+kk][jbase+jj]

    const float* A = alpha + (size_t)b * NN * NN;

#pragma unroll
    for (int i = 0; i < 16; ++i) {
        const int r = i * 4 + r0;                       // k-row within tile
        at[c][r] = A[(kbase + r) * NN + jbase + c];     // coalesced read, padded store
    }
    __syncthreads();

    const float fb = (float)(b * NN);
#pragma unroll
    for (int i = 0; i < 16; ++i) {
        const int jj = i * 4 + r0;
        const int j  = jbase + jj;
        const int k  = kbase + c;
        if (k == j) continue;
        const float w = 0.5f * (A[j * NN + k] + at[jj][c]);
        const unsigned t   = (unsigned)k - ((k > j) ? 1u : 0u);
        const unsigned idx = (unsigned)b * EP + (unsigned)j * (NN - 1) + t;
        out[OFF_EI0 + idx] = fb + (float)j;
        out[OFF_EI1 + idx] = fb + (float)k;
        out[OFF_EW  + idx] = w;
    }
}

extern "C" void kernel_launch(void* const* d_in, const int* in_sizes, int n_in,
                              void* d_out, int out_size, void* d_ws, size_t ws_size,
                              hipStream_t stream) {
    const float* h    = (const float*)d_in[0];
    const float* W    = (const float*)d_in[1];
    const float* bvec = (const float*)d_in[2];
    const float* att  = (const float*)d_in[3];
    float* out = (float*)d_out;

    float* pj  = (float*)d_ws;                       // 4096*64 floats = 1 MB
    float* pkT = pj + (size_t)BB * NN * HH;          // 1 MB, h-major
    float* cj  = pkT + (size_t)BB * NN * HH;         // 16 KB
    float* dk  = cj + BB * NN;                       // 16 KB

    float* alpha = out + OFF_AL;

    k_proj <<<BB * NN / 8, 256, 0, stream>>>(h, W, bvec, att, pj, pkT, cj, dk);
    k_attn <<<BB * 64, 512, 0, stream>>>(pj, pkT, att, cj, dk, alpha);
    k_edges<<<BB * 64, 256, 0, stream>>>(alpha, out);
}